// Round 15
// baseline (210.546 us; speedup 1.0000x reference)
//
#include <hip/hip_runtime.h>

typedef unsigned short u16;
typedef unsigned int u32;
typedef __bf16 bf16x8 __attribute__((ext_vector_type(8)));
typedef float f32x4 __attribute__((ext_vector_type(4)));
typedef u16 u16x4 __attribute__((ext_vector_type(4)));
typedef u16 u16x8 __attribute__((ext_vector_type(8)));
typedef u32 u32x4 __attribute__((ext_vector_type(4)));

#define NB 64
#define NN 512
#define NH 12
#define HD 32
#define DIM 384

#define LOG2E 1.4426950408889634f
#define QSCALE 0.25503486f   // (1/sqrt(32)) * log2(e)

__device__ __forceinline__ u16 f2bf(float f) {
  __bf16 b = (__bf16)f;
  union { __bf16 b; u16 u; } v; v.b = b;
  return v.u;
}
__device__ __forceinline__ float lo16f(u32 w) {
  union { u32 u; float f; } v; v.u = w << 16;
  return v.f;
}
__device__ __forceinline__ float hi16f(u32 w) {
  union { u32 u; float f; } v; v.u = w & 0xffff0000u;
  return v.f;
}

// ---------------------------------------------------------------------------
// Kernel 1 (prep): blocks [0,6144): bias -> fragment-stream beR (16x16 frags).
//   blocks [6144,6360): W -> 16x16 A-frag stream Wf bf16:
//   Wf[cb 72][kk 12][lane 64][8]: j = cb*16+(lane&15), k = kk*32+(lane>>4)*8+e.
//   (cb 0..23 = Wq heads, 24..47 = Wk heads, 48..71 = Wv heads; head h = cb/2)
// ---------------------------------------------------------------------------
__global__ __launch_bounds__(256) void prep_k(const float* __restrict__ table,
                                              const int* __restrict__ rel,
                                              const float* __restrict__ Wq,
                                              const float* __restrict__ Wkv,
                                              u32* __restrict__ beR,
                                              u16* __restrict__ Wf) {
  int bid = blockIdx.x;
  if (bid < 6144) {
    int t = bid * 256 + threadIdx.x;   // 1,572,864 words
    int word = t & 3;
    int lane = (t >> 2) & 63;
    int mf   = (t >> 8) & 3;
    int wv   = (t >> 10) & 7;
    int kt   = (t >> 13) & 15;
    int h    = t >> 17;
    int lr = lane & 15, lg = lane >> 4;
    int q = wv * 64 + mf * 16 + lr;
    int k = kt * 32 + (word >> 1) * 16 + lg * 4 + (word & 1) * 2;
    int i0 = rel[q * NN + k];
    int i1 = rel[q * NN + k + 1];
    u16 b0 = f2bf(table[i0 * NH + h] * LOG2E);
    u16 b1 = f2bf(table[i1 * NH + h] * LOG2E);
    beR[t] = (u32)b0 | ((u32)b1 << 16);
  } else {
    int t2 = (bid - 6144) * 256 + threadIdx.x;   // (cb*12+kk)*64+lane
    int lane = t2 & 63;
    int kk = (t2 >> 6) % 12;
    int cb = t2 / (12 * 64);
    int j = cb * 16 + (lane & 15);
    int k = kk * 32 + (lane >> 4) * 8;
    const float* wrow = (j < 384) ? (Wq + (size_t)j * DIM) : (Wkv + (size_t)(j - 384) * DIM);
    float4 a = *(const float4*)(wrow + k);
    float4 b = *(const float4*)(wrow + k + 4);
    u16x8 o = {f2bf(a.x), f2bf(a.y), f2bf(a.z), f2bf(a.w),
               f2bf(b.x), f2bf(b.y), f2bf(b.z), f2bf(b.w)};
    *(u16x8*)(Wf + (size_t)t2 * 8) = o;
  }
}

// ---------------------------------------------------------------------------
// Kernel 2 (fused): per (b,h) block computes Q,K,V projections INTO LDS/regs,
// then runs attention. No q/k/v HBM intermediates.
//   Wave w owns rows [w*64, w*64+64) for proj AND attn.
//   Q: mfma(Wq,x1) -> bounce via Ks rows (wave-local) -> qf regs.
//   K: mfma(Wk,x2) -> Ks[key][d].  V: mfma(x2,Wv) -> Vtp[d][perm-col] (8B).
//   One barrier, then the proven attn loop (beR bias as C-operand, exp2).
// ---------------------------------------------------------------------------
__global__ __launch_bounds__(512, 2) void fused_k(const float* __restrict__ x1,
                                                  const float* __restrict__ x2,
                                                  const float* __restrict__ qb,
                                                  const float* __restrict__ vb,
                                                  const u16* __restrict__ Wf,
                                                  const u32* __restrict__ beR,
                                                  float* __restrict__ out) {
  const int g = blockIdx.x;                 // 0..767
  const int vv = (g & 7) * 96 + (g >> 3);   // XCD cluster: 8 batches/XCD
  const int b = vv / 12, h = vv % 12;

  __shared__ u16 Ks[NN][40];     // [key][d] (also Q bounce buffer)
  __shared__ u16 Vtp[HD][520];   // [d][key-permuted]

  const int tid = threadIdx.x;
  const int lane = tid & 63, w = tid >> 6;
  const int lg = lane >> 4, lr = lane & 15;
  const int q0 = w * 64;

  // ---------------- proj: Q ----------------
  const float* x1w = x1 + ((size_t)b * NN + q0 + lr) * DIM + lg * 8;
  const u16* wfQ = Wf + ((size_t)(2 * h) * 12 * 64 + lane) * 8;   // nf:+6144, kk:+512
  f32x4 aq[4][2] = {};
#pragma unroll
  for (int kk = 0; kk < 12; ++kk) {
    bf16x8 af[4];
#pragma unroll
    for (int mf = 0; mf < 4; ++mf) {
      const float* p = x1w + (size_t)mf * 16 * DIM + kk * 32;
      float4 a = *(const float4*)p;
      float4 c = *(const float4*)(p + 4);
      af[mf] = (bf16x8){(__bf16)a.x, (__bf16)a.y, (__bf16)a.z, (__bf16)a.w,
                        (__bf16)c.x, (__bf16)c.y, (__bf16)c.z, (__bf16)c.w};
    }
    bf16x8 wq0 = *(const bf16x8*)(wfQ + (size_t)kk * 512);
    bf16x8 wq1 = *(const bf16x8*)(wfQ + (size_t)(12 + kk) * 512);
#pragma unroll
    for (int mf = 0; mf < 4; ++mf) {
      aq[mf][0] = __builtin_amdgcn_mfma_f32_16x16x32_bf16(wq0, af[mf], aq[mf][0], 0, 0, 0);
      aq[mf][1] = __builtin_amdgcn_mfma_f32_16x16x32_bf16(wq1, af[mf], aq[mf][1], 0, 0, 0);
    }
  }
  // bounce Q through this wave's Ks rows: Ks[q][d] = (Q + qb)*QSCALE
#pragma unroll
  for (int nf = 0; nf < 2; ++nf) {
    float4 qbv = *(const float4*)(qb + h * 32 + nf * 16 + lg * 4);
#pragma unroll
    for (int mf = 0; mf < 4; ++mf) {
      u16x4 o = {f2bf((aq[mf][nf][0] + qbv.x) * QSCALE),
                 f2bf((aq[mf][nf][1] + qbv.y) * QSCALE),
                 f2bf((aq[mf][nf][2] + qbv.z) * QSCALE),
                 f2bf((aq[mf][nf][3] + qbv.w) * QSCALE)};
      *(u16x4*)&Ks[q0 + mf * 16 + lr][nf * 16 + lg * 4] = o;
    }
  }
  bf16x8 qf[4];
#pragma unroll
  for (int mf = 0; mf < 4; ++mf)
    qf[mf] = *(const bf16x8*)&Ks[q0 + mf * 16 + lr][lg * 8];

  // ---------------- proj: K, V ----------------
  const float* x2w = x2 + ((size_t)b * NN + q0 + lr) * DIM + lg * 8;
  const u16* wfK = Wf + ((size_t)(24 + 2 * h) * 12 * 64 + lane) * 8;
  const u16* wfV = Wf + ((size_t)(48 + 2 * h) * 12 * 64 + lane) * 8;
  f32x4 ak[4][2] = {}, av[4][2] = {};
#pragma unroll
  for (int kk = 0; kk < 12; ++kk) {
    bf16x8 af[4];
#pragma unroll
    for (int mf = 0; mf < 4; ++mf) {
      const float* p = x2w + (size_t)mf * 16 * DIM + kk * 32;
      float4 a = *(const float4*)p;
      float4 c = *(const float4*)(p + 4);
      af[mf] = (bf16x8){(__bf16)a.x, (__bf16)a.y, (__bf16)a.z, (__bf16)a.w,
                        (__bf16)c.x, (__bf16)c.y, (__bf16)c.z, (__bf16)c.w};
    }
    bf16x8 wk0 = *(const bf16x8*)(wfK + (size_t)kk * 512);
    bf16x8 wk1 = *(const bf16x8*)(wfK + (size_t)(12 + kk) * 512);
    bf16x8 wv0 = *(const bf16x8*)(wfV + (size_t)kk * 512);
    bf16x8 wv1 = *(const bf16x8*)(wfV + (size_t)(12 + kk) * 512);
#pragma unroll
    for (int mf = 0; mf < 4; ++mf) {
      ak[mf][0] = __builtin_amdgcn_mfma_f32_16x16x32_bf16(wk0, af[mf], ak[mf][0], 0, 0, 0);
      ak[mf][1] = __builtin_amdgcn_mfma_f32_16x16x32_bf16(wk1, af[mf], ak[mf][1], 0, 0, 0);
      av[mf][0] = __builtin_amdgcn_mfma_f32_16x16x32_bf16(af[mf], wv0, av[mf][0], 0, 0, 0);
      av[mf][1] = __builtin_amdgcn_mfma_f32_16x16x32_bf16(af[mf], wv1, av[mf][1], 0, 0, 0);
    }
  }
  // store K: Ks[key][d]  (overwrites this wave's Q bounce region — qf already read)
#pragma unroll
  for (int mf = 0; mf < 4; ++mf)
#pragma unroll
    for (int nf = 0; nf < 2; ++nf) {
      u16x4 o = {f2bf(ak[mf][nf][0]), f2bf(ak[mf][nf][1]),
                 f2bf(ak[mf][nf][2]), f2bf(ak[mf][nf][3])};
      *(u16x4*)&Ks[q0 + mf * 16 + lr][nf * 16 + lg * 4] = o;
    }
  // store V: lane holds d = nf*16+lr, keys mf*16+lg*4+r -> perm cols 8lg+4(mf&1)+r
#pragma unroll
  for (int mf = 0; mf < 4; ++mf) {
    int colb = q0 + (mf >> 1) * 32 + 8 * lg + 4 * (mf & 1);
#pragma unroll
    for (int nf = 0; nf < 2; ++nf) {
      int d = nf * 16 + lr;
      float bv = vb[h * 32 + d];
      u16x4 o = {f2bf(av[mf][nf][0] + bv), f2bf(av[mf][nf][1] + bv),
                 f2bf(av[mf][nf][2] + bv), f2bf(av[mf][nf][3] + bv)};
      *(u16x4*)&Vtp[d][colb] = o;
    }
  }
  __syncthreads();

  // ---------------- attention ----------------
  const u32* bstream = beR + ((((size_t)h * 16) * 8 + w) * 4) * 256 + lane * 4;

  f32x4 accOT[4][2] = {};
  float lsum[4] = {0.f, 0.f, 0.f, 0.f};

  for (int kt = 0; kt < 16; ++kt) {
    const int k0 = kt * 32;
    const u32* bkt = bstream + (size_t)kt * 8192;
    bf16x8 kf0 = *(const bf16x8*)&Ks[k0 + lr][lg * 8];
    bf16x8 kf1 = *(const bf16x8*)&Ks[k0 + 16 + lr][lg * 8];
    bf16x8 vp0 = *(const bf16x8*)&Vtp[lr][k0 + lg * 8];
    bf16x8 vp1 = *(const bf16x8*)&Vtp[16 + lr][k0 + lg * 8];
#pragma unroll
    for (int mf = 0; mf < 4; ++mf) {
      u32x4 bbv = *(const u32x4*)(bkt + mf * 256);
      f32x4 c0 = {lo16f(bbv.x), hi16f(bbv.x), lo16f(bbv.y), hi16f(bbv.y)};
      f32x4 c1 = {lo16f(bbv.z), hi16f(bbv.z), lo16f(bbv.w), hi16f(bbv.w)};
      f32x4 s0 = __builtin_amdgcn_mfma_f32_16x16x32_bf16(kf0, qf[mf], c0, 0, 0, 0);
      f32x4 s1 = __builtin_amdgcn_mfma_f32_16x16x32_bf16(kf1, qf[mf], c1, 0, 0, 0);
      float p0[4], p1[4];
#pragma unroll
      for (int r = 0; r < 4; ++r) {
        p0[r] = __builtin_amdgcn_exp2f(s0[r]);
        p1[r] = __builtin_amdgcn_exp2f(s1[r]);
      }
      lsum[mf] += ((p0[0] + p0[1]) + (p0[2] + p0[3])) +
                  ((p1[0] + p1[1]) + (p1[2] + p1[3]));
      bf16x8 pv = {(__bf16)p0[0], (__bf16)p0[1], (__bf16)p0[2], (__bf16)p0[3],
                   (__bf16)p1[0], (__bf16)p1[1], (__bf16)p1[2], (__bf16)p1[3]};
      accOT[mf][0] = __builtin_amdgcn_mfma_f32_16x16x32_bf16(vp0, pv, accOT[mf][0], 0, 0, 0);
      accOT[mf][1] = __builtin_amdgcn_mfma_f32_16x16x32_bf16(vp1, pv, accOT[mf][1], 0, 0, 0);
    }
  }

  float linv[4];
#pragma unroll
  for (int mf = 0; mf < 4; ++mf) {
    float s = lsum[mf];
    s += __shfl_xor(s, 16, 64);
    s += __shfl_xor(s, 32, 64);
    linv[mf] = 1.0f / s;
  }

  float* outp = out + ((size_t)b * NN) * DIM + h * HD;
#pragma unroll
  for (int mf = 0; mf < 4; ++mf) {
    int q = q0 + mf * 16 + lr;
#pragma unroll
    for (int nf = 0; nf < 2; ++nf) {
      float4 o = {accOT[mf][nf][0] * linv[mf], accOT[mf][nf][1] * linv[mf],
                  accOT[mf][nf][2] * linv[mf], accOT[mf][nf][3] * linv[mf]};
      *(float4*)&outp[(size_t)q * DIM + nf * 16 + lg * 4] = o;
    }
  }
}

// ---------------------------------------------------------------------------
extern "C" void kernel_launch(void* const* d_in, const int* in_sizes, int n_in,
                              void* d_out, int out_size, void* d_ws, size_t ws_size,
                              hipStream_t stream) {
  const float* x1    = (const float*)d_in[0];
  const float* x2    = (const float*)d_in[1];
  const float* Wq    = (const float*)d_in[2];
  const float* Wkv   = (const float*)d_in[3];
  const float* qb    = (const float*)d_in[4];
  const float* vb    = (const float*)d_in[5];
  const float* table = (const float*)d_in[6];
  const int*   rel   = (const int*)d_in[7];
  float* out = (float*)d_out;

  u32* beR = (u32*)d_ws;                       // 1,572,864 u32 = 6.3 MB
  u16* Wf  = (u16*)(beR + 1572864);            // 442,368 u16 = 0.88 MB

  prep_k<<<6360, 256, 0, stream>>>(table, rel, Wq, Wkv, beR, Wf);
  fused_k<<<NB * NH, 512, 0, stream>>>(x1, x2, qb, vb, Wf, beR, out);
}